// Round 1
// 129.253 us; speedup vs baseline: 1.0492x; 1.0492x over previous
//
#include <hip/hip_runtime.h>
#include <math.h>

// Problem constants: B=2, N=256, C=5, H=4, DH=8, HID=32, FF=20
#define BB 2
#define NN 256
#define CC 5
#define HIDD 32

// Round-1 (this session): fuse prep into edge_attn. Measurement is dominated
// by harness workspace-poison fills (~3x39.5us); the controllable tail is the
// serial 3-kernel chain. Each edge block is now self-sufficient:
//  - yk/yv/q0 projections recomputed per block in registers (46 MFLOP total)
//  - PWL table (A,B,C,D over 33 dist-bins) built per block directly in LDS
//  - 2-hop adjacency via neighbor-list: (A@A)[i][j]>0 <=> exists m in N(i)
//    with adj[m][j] (adj symmetric) -> ~15 coalesced row reads, no bitmasks.
// FP op order kept identical to the 132us 3-kernel version (absmax 0.0).

__device__ __forceinline__ float gelu_tanh(float x) {
    float x3 = x * x * x;
    return 0.5f * x * (1.0f + tanhf(0.7978845608028654f * (x + 0.044715f * x3)));
}
__device__ __forceinline__ float sgnf(float x) {
    return (x > 0.f) ? 1.f : ((x < 0.f) ? -1.f : 0.f);
}

#define TROW 9           // table row = 9 float4 = 36 floats (32 used + pad)
#define TSZ (33 * TROW)  // one table, in float4 units

// ---- Kernel 1: fully fused edge attention. One block per (b,i). ----
__global__ __launch_bounds__(256) void fused_attn(
    const float* __restrict__ coors,
    const int* __restrict__ adj,
    const float* __restrict__ feats,
    const float* __restrict__ Wq0, const float* __restrict__ Mk0, const float* __restrict__ Mv0,
    const float* __restrict__ gnA0, const float* __restrict__ bnA0,
    const float* __restrict__ R1, const float* __restrict__ rb1,
    const float* __restrict__ R2, const float* __restrict__ rb2,
    const float* __restrict__ Wo0,  // (32,5)
    const float* __restrict__ gnF0, const float* __restrict__ bnF0,
    const float* __restrict__ Wf10, // (C,20)
    const float* __restrict__ Wf20, // (20,C)
    float* __restrict__ xfin)       // (512,5) final scalar features
{
    int node = blockIdx.x;
    int b = node >> 8, i = node & 255;
    int tid = threadIdx.x;
    int j = tid;
    int lane = tid & 63, wave = tid >> 6;

    __shared__ float4 sT[4 * TSZ];          // A|B|C|D tables, rows padded to 9 f4
    __shared__ float R2k[32][32];           // R2[w][hd]       (k00 cols 0:32)
    __shared__ float R2v[32][32];           // R2[w][192+hd]   (v00 cols 192:224)
    __shared__ float sR1[32], srb1[32], tt[32], sts[32];
    __shared__ float q0s[32];
    __shared__ float Wo0t[5][32];
    __shared__ int nlist[NN];
    __shared__ int ncnt;
    __shared__ float wredm[4][4], wreds[4][4], hm[4], hs[4];
    __shared__ float ew[4][5], x0as[5], xfs[5], h0s[20];

    // ---- R0: stage weights, own adjacency entry, dist, own-node LN ----
    int av = adj[(size_t)(b * NN + i) * NN + j];   // adj[i][j], this thread's j

    for (int idx = tid; idx < 1024; idx += 256) {
        int w = idx >> 5, hd = idx & 31;
        R2k[w][hd] = R2[w * 384 + hd];
        R2v[w][hd] = R2[w * 384 + 192 + hd];
    }
    if (tid < 32) { sR1[tid] = R1[tid]; srb1[tid] = rb1[tid]; }
    if (tid < 160) Wo0t[tid / 32][tid % 32] = Wo0[(tid % 32) * 5 + tid / 32];
    if (tid == 0) ncnt = 0;

    // dist(i,j)
    float dx = coors[(b * NN + j) * 3 + 0] - coors[(b * NN + i) * 3 + 0];
    float dy = coors[(b * NN + j) * 3 + 1] - coors[(b * NN + i) * 3 + 1];
    float dz = coors[(b * NN + j) * 3 + 2] - coors[(b * NN + i) * 3 + 2];
    float dist = sqrtf(dx * dx + dy * dy + dz * dz + 1e-12f);

    // own node-j normalized scalar features x0n (same op order as old prep)
    float x0n[CC];
    {
        const float* f = feats + (size_t)(b * NN + j) * CC;
        float fv[CC], n0[CC];
        float mu = 0.f;
#pragma unroll
        for (int c = 0; c < CC; c++) { fv[c] = f[c]; n0[c] = fabsf(fv[c]); mu += n0[c]; }
        mu *= (1.0f / CC);
        float var = 0.f;
#pragma unroll
        for (int c = 0; c < CC; c++) { float d = n0[c] - mu; var += d * d; }
        var *= (1.0f / CC);
        float sd = sqrtf(var) + 1e-8f;
#pragma unroll
        for (int c = 0; c < CC; c++) {
            float ln = (n0[c] - mu) / sd * gnA0[c] + bnA0[c];
            x0n[c] = sgnf(fv[c]) * gelu_tanh(ln);
        }
    }

    __syncthreads();

    // ---- R1: ReLU knots | neighbor list | q0(i) | yk(j) projection ----
    if (tid < 32) {
        float r = sR1[tid];
        tt[tid] = (r != 0.f) ? (-srb1[tid] / r) : -3.0e38f;
    }
    if (av) { int p = atomicAdd(&ncnt, 1); nlist[p] = j; }
    if (tid < 32) {
        // q0[i][tid]: recompute x0n for node i (32-way redundant, trivial)
        const float* f = feats + (size_t)(b * NN + i) * CC;
        float fv[CC], n0[CC], xi[CC];
        float mu = 0.f;
#pragma unroll
        for (int c = 0; c < CC; c++) { fv[c] = f[c]; n0[c] = fabsf(fv[c]); mu += n0[c]; }
        mu *= (1.0f / CC);
        float var = 0.f;
#pragma unroll
        for (int c = 0; c < CC; c++) { float d = n0[c] - mu; var += d * d; }
        var *= (1.0f / CC);
        float sd = sqrtf(var) + 1e-8f;
#pragma unroll
        for (int c = 0; c < CC; c++) {
            float ln = (n0[c] - mu) / sd * gnA0[c] + bnA0[c];
            xi[c] = sgnf(fv[c]) * gelu_tanh(ln);
        }
        float q = 0.f;
#pragma unroll
        for (int c = 0; c < CC; c++) q = fmaf(xi[c], Wq0[c * HIDD + tid], q);
        q0s[tid] = q;
    }
    // yk[j][0..31] in registers (same accumulation order as old prep)
    float ykr[32];
#pragma unroll
    for (int hd = 0; hd < 32; hd++) ykr[hd] = 0.f;
#pragma unroll
    for (int c = 0; c < CC; c++) {
        float xc = x0n[c];
#pragma unroll
        for (int hd = 0; hd < 32; hd++)
            ykr[hd] = fmaf(xc, Mk0[c * HIDD + hd], ykr[hd]);
    }
    __syncthreads();

    // ---- R2: rank-sort knots | 2-hop adjacency mask (overlapped) ----
    if (tid < 32) {
        float t = tt[tid];
        int rank = 0;
        for (int k = 0; k < 32; k++) {
            float tk = tt[k];
            rank += (tk < t) || (tk == t && k < tid);
        }
        sts[rank] = t;
    }
    int okacc = (av != 0) || (i == j);
    {
        int cnt = ncnt;
        for (int t = 0; t < cnt; t++) {
            int m = nlist[t];
            okacc |= adj[(size_t)(b * NN + m) * NN + j];  // coalesced over j
        }
    }
    __syncthreads();

    // ---- R3: build piecewise-linear tables directly in LDS ----
    for (int idx = tid; idx < 33 * 32; idx += 256) {
        int p = idx >> 5, hd = idx & 31;
        float rep = (p == 0) ? (sts[0] - 1.0f)
                  : (p == 32) ? (sts[31] + 1.0f)
                  : 0.5f * (sts[p - 1] + sts[p]);
        float A = 0.f, Bv = 0.f, Cv = 0.f, Dv = 0.f;
        for (int w = 0; w < 32; w++) {
            float r = sR1[w], bb = srb1[w];
            if (fmaf(r, rep, bb) > 0.f) {
                float rk = R2k[w][hd];
                float rv = R2v[w][hd];
                A = fmaf(r, rk, A); Bv = fmaf(bb, rk, Bv);
                Cv = fmaf(r, rv, Cv); Dv = fmaf(bb, rv, Dv);
            }
        }
        Bv += rb2[hd];          // fold second-layer bias
        Dv += rb2[192 + hd];
        float* tf = (float*)sT;
        tf[(0 * TSZ + p * TROW) * 4 + hd] = A;
        tf[(1 * TSZ + p * TROW) * 4 + hd] = Bv;
        tf[(2 * TSZ + p * TROW) * 4 + hd] = Cv;
        tf[(3 * TSZ + p * TROW) * 4 + hd] = Dv;
    }
    __syncthreads();

    // ---- R4: logits via PWL table ----
    int p = 0;
#pragma unroll
    for (int k = 0; k < 32; k++) p += (sts[k] < dist) ? 1 : 0;

    const float4* Ap = sT + 0 * TSZ + p * TROW;
    const float4* Bp = sT + 1 * TSZ + p * TROW;
    const float4* Cp = sT + 2 * TSZ + p * TROW;
    const float4* Dp = sT + 3 * TSZ + p * TROW;
    const float4* q04 = (const float4*)q0s;

    float lg[4] = {0.f, 0.f, 0.f, 0.f};
#pragma unroll
    for (int q = 0; q < 8; q++) {
        float4 a = Ap[q], bb = Bp[q], qq = q04[q];
        int h = q >> 1;
        lg[h] = fmaf(fmaf(dist, a.x, bb.x) * qq.x, ykr[4 * q + 0], lg[h]);
        lg[h] = fmaf(fmaf(dist, a.y, bb.y) * qq.y, ykr[4 * q + 1], lg[h]);
        lg[h] = fmaf(fmaf(dist, a.z, bb.z) * qq.z, ykr[4 * q + 2], lg[h]);
        lg[h] = fmaf(fmaf(dist, a.w, bb.w) * qq.w, ykr[4 * q + 3], lg[h]);
    }
    {
        const float invs = 0.35355339059327379f; // 1/sqrt(8)
        bool ok = okacc != 0;
#pragma unroll
        for (int h = 0; h < 4; h++) lg[h] = ok ? lg[h] * invs : -1e9f;
    }

    // block softmax over j, per head (identical structure/op order)
    float attn[4];
#pragma unroll
    for (int h = 0; h < 4; h++) {
        float v = lg[h];
        for (int off = 32; off; off >>= 1) v = fmaxf(v, __shfl_xor(v, off, 64));
        if (lane == 0) wredm[h][wave] = v;
    }
    __syncthreads();
    if (tid < 4) hm[tid] = fmaxf(fmaxf(wredm[tid][0], wredm[tid][1]), fmaxf(wredm[tid][2], wredm[tid][3]));
    __syncthreads();
#pragma unroll
    for (int h = 0; h < 4; h++) lg[h] = expf(lg[h] - hm[h]);
#pragma unroll
    for (int h = 0; h < 4; h++) {
        float v = lg[h];
        for (int off = 32; off; off >>= 1) v += __shfl_xor(v, off, 64);
        if (lane == 0) wreds[h][wave] = v;
    }
    __syncthreads();
    if (tid < 4) hs[tid] = wreds[tid][0] + wreds[tid][1] + wreds[tid][2] + wreds[tid][3];
    __syncthreads();
#pragma unroll
    for (int h = 0; h < 4; h++) attn[h] = lg[h] / hs[h];

    // yv[j][0..31] projected here (after softmax) to keep VGPR peak low
    float yvr[32];
#pragma unroll
    for (int hd = 0; hd < 32; hd++) yvr[hd] = 0.f;
#pragma unroll
    for (int c = 0; c < CC; c++) {
        float xc = x0n[c];
#pragma unroll
        for (int hd = 0; hd < 32; hd++)
            yvr[hd] = fmaf(xc, Mv0[c * HIDD + hd], yvr[hd]);
    }

    // v-phase with Wo0 folded: e[c] = sum_hd attn*(dist*C+D)[hd]*yv[hd]*Wo0[hd][c]
    float e[5] = {0.f, 0.f, 0.f, 0.f, 0.f};
#pragma unroll
    for (int q = 0; q < 8; q++) {
        float4 c4 = Cp[q], d4 = Dp[q];
        float at = attn[q >> 1];
        float4 pv;
        pv.x = at * fmaf(dist, c4.x, d4.x) * yvr[4 * q + 0];
        pv.y = at * fmaf(dist, c4.y, d4.y) * yvr[4 * q + 1];
        pv.z = at * fmaf(dist, c4.z, d4.z) * yvr[4 * q + 2];
        pv.w = at * fmaf(dist, c4.w, d4.w) * yvr[4 * q + 3];
#pragma unroll
        for (int c = 0; c < 5; c++) {
            float4 w4 = ((const float4*)Wo0t[c])[q];
            e[c] = fmaf(pv.x, w4.x, fmaf(pv.y, w4.y, fmaf(pv.z, w4.z, fmaf(pv.w, w4.w, e[c]))));
        }
    }
    // block-reduce e[0..4]
    for (int off = 32; off; off >>= 1)
#pragma unroll
        for (int c = 0; c < 5; c++) e[c] += __shfl_xor(e[c], off, 64);
    if (lane == 0)
#pragma unroll
        for (int c = 0; c < 5; c++) ew[wave][c] = e[c];
    __syncthreads();

    // epilogue (identical to previous version)
    if (tid < 5) {
        float d0 = ew[0][tid] + ew[1][tid] + ew[2][tid] + ew[3][tid];
        x0as[tid] = feats[node * 5 + tid] + d0;
    }
    __syncthreads();
    if (tid < 5) {
        float x0a[5], n0[5];
        float mu = 0.f;
#pragma unroll
        for (int c = 0; c < 5; c++) { x0a[c] = x0as[c]; n0[c] = fabsf(x0a[c]); mu += n0[c]; }
        mu *= 0.2f;
        float var = 0.f;
#pragma unroll
        for (int c = 0; c < 5; c++) { float d = n0[c] - mu; var += d * d; }
        var *= 0.2f;
        float sd = sqrtf(var) + 1e-8f;
        float ln = (n0[tid] - mu) / sd * gnF0[tid] + bnF0[tid];
        xfs[tid] = sgnf(x0a[tid]) * gelu_tanh(ln);
    }
    __syncthreads();
    if (tid < 20) {
        float s = 0.f;
#pragma unroll
        for (int c = 0; c < 5; c++) s = fmaf(xfs[c], Wf10[c * 20 + tid], s);
        h0s[tid] = gelu_tanh(s);
    }
    __syncthreads();
    if (tid < 5) {
        float f0 = 0.f;
        for (int f = 0; f < 20; f++) f0 = fmaf(h0s[f], Wf20[f * 5 + tid], f0);
        xfin[node * 5 + tid] = x0as[tid] + f0;
    }
}

// ---- Kernel 2: mean-pool + 2-layer MLP head ----
__global__ __launch_bounds__(256) void head_mlp(const float* __restrict__ xfin,
                         const float* __restrict__ Wh1, const float* __restrict__ bh1,
                         const float* __restrict__ Wh2, const float* __restrict__ bh2,
                         float* __restrict__ out) {
    __shared__ float part[2][5][25];
    __shared__ float pooled[10];
    __shared__ float hdn[2][128];
    int tid = threadIdx.x;
    if (tid < 250) {
        int b = tid / 125, r = tid % 125, c = r / 25, grp = r % 25;
        float s = 0.f;
        for (int i = grp; i < NN; i += 25) s += xfin[(b * NN + i) * 5 + c];
        part[b][c][grp] = s;
    }
    __syncthreads();
    if (tid < 10) {
        int b = tid / 5, c = tid % 5;
        float s = 0.f;
        for (int g = 0; g < 25; g++) s += part[b][c][g];
        pooled[tid] = s * (1.0f / NN);
    }
    __syncthreads();
    {
        int b = tid >> 7, k = tid & 127;
        float s = bh1[k];
#pragma unroll
        for (int c = 0; c < 5; c++) s = fmaf(pooled[b * 5 + c], Wh1[c * 128 + k], s);
        hdn[b][k] = fmaxf(s, 0.f);
    }
    __syncthreads();
    if (tid < 18) {
        int b = tid / 9, o = tid % 9;
        float s = bh2[o];
        for (int k = 0; k < 128; k++) s = fmaf(hdn[b][k], Wh2[k * 9 + o], s);
        out[b * 9 + o] = s;
    }
}

extern "C" void kernel_launch(void* const* d_in, const int* in_sizes, int n_in,
                              void* d_out, int out_size, void* d_ws, size_t ws_size,
                              hipStream_t stream) {
    const float* feats = (const float*)d_in[0];
    const float* coors = (const float*)d_in[1];
    const int*   adj   = (const int*)d_in[2];
    const float* Wq    = (const float*)d_in[3];
    const float* Mk    = (const float*)d_in[4];
    const float* Mv    = (const float*)d_in[5];
    const float* R1    = (const float*)d_in[6];
    const float* rb1   = (const float*)d_in[7];
    const float* R2    = (const float*)d_in[8];
    const float* rb2   = (const float*)d_in[9];
    const float* Wo0   = (const float*)d_in[10];
    const float* gnA   = (const float*)d_in[12];
    const float* bnA   = (const float*)d_in[13];
    const float* gnF   = (const float*)d_in[14];
    const float* bnF   = (const float*)d_in[15];
    const float* Wf1   = (const float*)d_in[16];
    const float* Wf2   = (const float*)d_in[17];
    const float* Wh1   = (const float*)d_in[20];
    const float* bh1   = (const float*)d_in[21];
    const float* Wh2   = (const float*)d_in[22];
    const float* bh2   = (const float*)d_in[23];
    float* out = (float*)d_out;

    float* xfin = (float*)d_ws;   // 512*5 floats; fully written before head reads

    hipLaunchKernelGGL(fused_attn, dim3(512), dim3(256), 0, stream,
                       coors, adj, feats, Wq, Mk, Mv, gnA, bnA, R1, rb1, R2, rb2,
                       Wo0, gnF, bnF, Wf1, Wf2, xfin);
    hipLaunchKernelGGL(head_mlp, dim3(1), dim3(256), 0, stream,
                       xfin, Wh1, bh1, Wh2, bh2, out);
}